// Round 2
// baseline (1480.092 us; speedup 1.0000x reference)
//
#include <hip/hip_runtime.h>

typedef unsigned short u16;
typedef __attribute__((ext_vector_type(8))) short bf16x8;   // 8 x bf16 bits
typedef __attribute__((ext_vector_type(4))) float floatx4;

#define NSPOT 20000
#define NGENE 3000
#define E1N   640000
#define E2N   320000

// output element offsets (res, lam, h2, h4 concatenated)
#define OFF_RES 0
#define OFF_LAM 5120000
#define OFF_H2  5160000
#define OFF_H4  5480000

__device__ __forceinline__ float b2f(u16 u){
  union { unsigned int i; float f; } v; v.i = ((unsigned int)u) << 16; return v.f;
}
__device__ __forceinline__ u16 f2b(float f){
  union { float f; unsigned int i; } v; v.f = f;
  unsigned int i = v.i;
  return (u16)((i + 0x7FFFu + ((i >> 16) & 1u)) >> 16);
}
// store to output with runtime dtype
__device__ __forceinline__ void stout(void* O, size_t i, float v, int isbf){
  if (isbf) ((u16*)O)[i] = f2b(v); else ((float*)O)[i] = v;
}
// load input element as bf16 bits with runtime dtype
__device__ __forceinline__ u16 ldu(const void* p, size_t i, int isbf){
  return isbf ? ((const u16*)p)[i] : f2b(((const float*)p)[i]);
}

// ---------------- dtype sniffer: bf16 data has sane exponent fields at even u16s ----------------
__global__ void sniff_kernel(const u16* __restrict__ x, int* __restrict__ flag){
  int lane = threadIdx.x;           // 64 threads
  u16 u = x[lane * 2];              // even u16 = f32 low-mantissa half if data is f32
  int e = (u >> 7) & 0xFF;
  int sane = (u == 0) || (e >= 0x60 && e <= 0xA0);
  unsigned long long b = __ballot(sane);
  if (lane == 0) flag[0] = (__popcll(b) >= 48) ? 1 : 0;   // bf16:~64, f32:~16
}

// ---------------- small-array convert to bf16 scratch ----------------
__global__ void conv1d_kernel(const void* __restrict__ src, u16* __restrict__ dst, int n,
                              const int* __restrict__ dflag){
  int i = blockIdx.x * 256 + threadIdx.x;
  if (i < n) dst[i] = ldu(src, i, dflag[0]);
}

// ---------------- CSR build ----------------
__global__ void hist_kernel(const int* __restrict__ dst, int* __restrict__ cnt, int E){
  int e = blockIdx.x * 256 + threadIdx.x;
  if (e < E){ int d = dst[e]; if ((unsigned)d < (unsigned)NSPOT) atomicAdd(&cnt[d], 1); }
}

__global__ void scan_kernel(const int* __restrict__ cnt, int* __restrict__ off,
                            int* __restrict__ cur, int n){
  __shared__ int part[256];
  int tid = threadIdx.x;
  int chunk = (n + 255) / 256;
  int lo = tid * chunk; if (lo > n) lo = n;
  int hi = lo + chunk; if (hi > n) hi = n;
  int s = 0;
  for (int i = lo; i < hi; i++) s += cnt[i];
  part[tid] = s;
  __syncthreads();
  if (tid == 0){
    int run = 0;
    for (int i = 0; i < 256; i++){ int t = part[i]; part[i] = run; run += t; }
  }
  __syncthreads();
  int run = part[tid];
  for (int i = lo; i < hi; i++){ off[i] = run; cur[i] = run; run += cnt[i]; }
  if (hi == n) off[n] = run;
}

__global__ void scatter_kernel(const int* __restrict__ src, const int* __restrict__ dst,
                               int* __restrict__ cur, int* __restrict__ out, int E){
  int e = blockIdx.x * 256 + threadIdx.x;
  if (e < E){
    int d = dst[e];
    if ((unsigned)d < (unsigned)NSPOT){
      int p = atomicAdd(&cur[d], 1);
      if ((unsigned)p < (unsigned)E) out[p] = src[e];
    }
  }
}

// ---------------- weight concat: [Wl | Wr | Wlp | Wrp] -> bf16 [Kdim][768] ----------------
__global__ void assemble_kernel(const void* Wl, const void* bl, const void* Wr, const void* br,
                                const void* Wlp, const void* blp, const void* Wrp, const void* brp,
                                u16* __restrict__ Wcat, u16* __restrict__ bcat, int Kdim,
                                const int* __restrict__ dflag){
  int isbf = dflag[0];
  int idx = blockIdx.x * 256 + threadIdx.x;
  int total = Kdim * 768;
  if (idx < total){
    int k = idx / 768, j = idx % 768;
    int seg = j / 192, jj = j % 192;
    const void* W = (seg == 0) ? Wl : (seg == 1) ? Wr : (seg == 2) ? Wlp : Wrp;
    Wcat[idx] = ldu(W, (size_t)k * 192 + jj, isbf);
  }
  if (idx < 768){
    int seg = idx / 192, jj = idx % 192;
    const void* b = (seg == 0) ? bl : (seg == 1) ? br : (seg == 2) ? blp : brp;
    bcat[idx] = ldu(b, jj, isbf);
  }
}

// ---------------- MFMA GEMM: C[m,n] = sum_k A[m,k]*B[k,n] (+bias)(relu) ----------------
// A_KM: A[m,k] at A[k*lda+m] else A[m*lda+k]. B_NK: B[k,n] at B[n*ldb+k] else B[k*ldb+n].
// A_EXT/B_EXT: operand dtype follows runtime flag (input/out buffer), else bf16 ws.
// C_OUT: C dtype follows runtime flag (d_out), else bf16 ws.
template<bool A_KM, bool B_NK, bool A_EXT, bool B_EXT, bool RELU, bool HAS_BIAS, bool C_OUT>
__global__ __launch_bounds__(256) void gemm_mfma(
    const void* __restrict__ A, const void* __restrict__ B,
    const u16* __restrict__ bias, void* __restrict__ Cp,
    const int* __restrict__ dflag, size_t aoff, size_t coff,
    int M, int N, int K, int lda, int ldb, int ldc)
{
  const int isbf = dflag[0];
  constexpr int BM = 128, BN = 64, BK = 32, LDA = BK + 8, LDB = BK + 8;
  __shared__ __align__(16) u16 As[BM * LDA];
  __shared__ __align__(16) u16 Bs[BN * LDB];
  const u16*   A16 = (const u16*)A + aoff;
  const float* A32 = (const float*)A + aoff;
  const u16*   B16 = (const u16*)B;
  const float* B32 = (const float*)B;
  auto ldA = [&](size_t i) -> u16 { return (!A_EXT || isbf) ? A16[i] : f2b(A32[i]); };
  auto ldB = [&](size_t i) -> u16 { return (!B_EXT || isbf) ? B16[i] : f2b(B32[i]); };

  int tid = threadIdx.x;
  int lane = tid & 63, w = tid >> 6;
  int m0 = blockIdx.y * BM, n0 = blockIdx.x * BN;
  floatx4 acc[2][4] = {};
  int quad = lane >> 4;
  int nk = (K + BK - 1) / BK;
  for (int kt = 0; kt < nk; kt++){
    int k0 = kt * BK;
    // ---- stage A -> As[m][k] ----
    if (!A_KM){
#pragma unroll
      for (int i = 0; i < 2; i++){
        int id = tid + i * 256;
        int r = id >> 2, c = (id & 3) * 8;
        int gm = m0 + r, gk = k0 + c;
        if (gm < M && gk + 8 <= K){
          if (!A_EXT || isbf){
            uint4 v = *(const uint4*)(A16 + (size_t)gm * lda + gk);
            *(uint4*)&As[r * LDA + c] = v;
          } else {
            const float* p = A32 + (size_t)gm * lda + gk;
            float4 f0 = *(const float4*)p, f1 = *(const float4*)(p + 4);
            u16* d = &As[r * LDA + c];
            d[0]=f2b(f0.x); d[1]=f2b(f0.y); d[2]=f2b(f0.z); d[3]=f2b(f0.w);
            d[4]=f2b(f1.x); d[5]=f2b(f1.y); d[6]=f2b(f1.z); d[7]=f2b(f1.w);
          }
        } else {
          for (int e = 0; e < 8; e++)
            As[r * LDA + c + e] = (gm < M && gk + e < K) ? ldA((size_t)gm * lda + gk + e) : (u16)0;
        }
      }
    } else {
#pragma unroll
      for (int i = 0; i < 2; i++){
        int id = tid + i * 256;
        int kk = id >> 4, rr = (id & 15) * 8;
        int gk = k0 + kk, gm = m0 + rr;
        if (gk < K && gm + 8 <= M){
          if (!A_EXT || isbf){
            uint4 v = *(const uint4*)(A16 + (size_t)gk * lda + gm);
            const u16* pv = (const u16*)&v;
#pragma unroll
            for (int e = 0; e < 8; e++) As[(rr + e) * LDA + kk] = pv[e];
          } else {
            const float* p = A32 + (size_t)gk * lda + gm;
            float4 f0 = *(const float4*)p, f1 = *(const float4*)(p + 4);
            As[(rr+0)*LDA+kk]=f2b(f0.x); As[(rr+1)*LDA+kk]=f2b(f0.y);
            As[(rr+2)*LDA+kk]=f2b(f0.z); As[(rr+3)*LDA+kk]=f2b(f0.w);
            As[(rr+4)*LDA+kk]=f2b(f1.x); As[(rr+5)*LDA+kk]=f2b(f1.y);
            As[(rr+6)*LDA+kk]=f2b(f1.z); As[(rr+7)*LDA+kk]=f2b(f1.w);
          }
        } else {
          for (int e = 0; e < 8; e++)
            As[(rr + e) * LDA + kk] = (gk < K && gm + e < M) ? ldA((size_t)gk * lda + gm + e) : (u16)0;
        }
      }
    }
    // ---- stage B -> Bs[n][k] ----
    if (B_NK){
      int r = tid >> 2, c = (tid & 3) * 8;
      int gn = n0 + r, gk = k0 + c;
      if (gn < N && gk + 8 <= K){
        if (!B_EXT || isbf){
          uint4 v = *(const uint4*)(B16 + (size_t)gn * ldb + gk);
          *(uint4*)&Bs[r * LDB + c] = v;
        } else {
          const float* p = B32 + (size_t)gn * ldb + gk;
          float4 f0 = *(const float4*)p, f1 = *(const float4*)(p + 4);
          u16* d = &Bs[r * LDB + c];
          d[0]=f2b(f0.x); d[1]=f2b(f0.y); d[2]=f2b(f0.z); d[3]=f2b(f0.w);
          d[4]=f2b(f1.x); d[5]=f2b(f1.y); d[6]=f2b(f1.z); d[7]=f2b(f1.w);
        }
      } else {
        for (int e = 0; e < 8; e++)
          Bs[r * LDB + c + e] = (gn < N && gk + e < K) ? ldB((size_t)gn * ldb + gk + e) : (u16)0;
      }
    } else {
      int kk = tid >> 3, nn = (tid & 7) * 8;
      int gk = k0 + kk, gn = n0 + nn;
      if (gk < K && gn + 8 <= N){
        if (!B_EXT || isbf){
          uint4 v = *(const uint4*)(B16 + (size_t)gk * ldb + gn);
          const u16* pv = (const u16*)&v;
#pragma unroll
          for (int e = 0; e < 8; e++) Bs[(nn + e) * LDB + kk] = pv[e];
        } else {
          const float* p = B32 + (size_t)gk * ldb + gn;
          float4 f0 = *(const float4*)p, f1 = *(const float4*)(p + 4);
          Bs[(nn+0)*LDB+kk]=f2b(f0.x); Bs[(nn+1)*LDB+kk]=f2b(f0.y);
          Bs[(nn+2)*LDB+kk]=f2b(f0.z); Bs[(nn+3)*LDB+kk]=f2b(f0.w);
          Bs[(nn+4)*LDB+kk]=f2b(f1.x); Bs[(nn+5)*LDB+kk]=f2b(f1.y);
          Bs[(nn+6)*LDB+kk]=f2b(f1.z); Bs[(nn+7)*LDB+kk]=f2b(f1.w);
        }
      } else {
        for (int e = 0; e < 8; e++)
          Bs[(nn + e) * LDB + kk] = (gk < K && gn + e < N) ? ldB((size_t)gk * ldb + gn + e) : (u16)0;
      }
    }
    __syncthreads();
    // ---- MFMA ----
    bf16x8 af[2];
#pragma unroll
    for (int mi = 0; mi < 2; mi++)
      af[mi] = *(const bf16x8*)&As[(w * 32 + mi * 16 + (lane & 15)) * LDA + quad * 8];
#pragma unroll
    for (int ni = 0; ni < 4; ni++){
      bf16x8 bfr = *(const bf16x8*)&Bs[(ni * 16 + (lane & 15)) * LDB + quad * 8];
#pragma unroll
      for (int mi = 0; mi < 2; mi++)
        acc[mi][ni] = __builtin_amdgcn_mfma_f32_16x16x32_bf16(af[mi], bfr, acc[mi][ni], 0, 0, 0);
    }
    __syncthreads();
  }
  // ---- epilogue ----
#pragma unroll
  for (int mi = 0; mi < 2; mi++)
#pragma unroll
    for (int ni = 0; ni < 4; ni++)
#pragma unroll
      for (int r = 0; r < 4; r++){
        int row = m0 + w * 32 + mi * 16 + quad * 4 + r;
        int col = n0 + ni * 16 + (lane & 15);
        if (row < M && col < N){
          float v = acc[mi][ni][r];
          if (HAS_BIAS) v += b2f(bias[col]);
          if (RELU) v = fmaxf(v, 0.f);
          size_t ci = coff + (size_t)row * ldc + col;
          if (!C_OUT) ((u16*)Cp)[ci] = f2b(v);
          else stout(Cp, ci, v, isbf);
        }
      }
}

// ---------------- GATv2 aggregation: one wave per dst, online softmax ----------------
__global__ __launch_bounds__(256) void gat_kernel(
    const u16* __restrict__ Y, int xl_off, int xr_off,
    const int* __restrict__ off, const int* __restrict__ srcs,
    const u16* __restrict__ att, const u16* __restrict__ bias,
    u16* __restrict__ aggout, int out_off, int n, int E)
{
  int wid = (blockIdx.x * 256 + threadIdx.x) >> 6;
  int lane = threadIdx.x & 63;
  if (wid >= n) return;
  const int ldY = 768;
  size_t drow = (size_t)wid * ldY;
  float xr0 = b2f(Y[drow + xr_off + lane]);
  float xr1 = b2f(Y[drow + xr_off + 64 + lane]);
  float xr2 = b2f(Y[drow + xr_off + 128 + lane]);
  float at0 = b2f(att[lane]), at1 = b2f(att[64 + lane]), at2 = b2f(att[128 + lane]);
  float mh0 = -INFINITY, mh1 = -INFINITY, mh2 = -INFINITY;
  float lh0 = 0.f, lh1 = 0.f, lh2 = 0.f;
  float ac0 = 0.f, ac1 = 0.f, ac2 = 0.f;
  int beg = off[wid], end = off[wid + 1];
  beg = max(0, min(beg, E));
  end = max(beg, min(end, E));
  for (int i = beg; i < end; i++){
    int s = srcs[i];
    if ((unsigned)s >= (unsigned)NSPOT) s = 0;
    const u16* base = Y + (size_t)s * ldY + xl_off + lane;
    float x0 = b2f(base[0]), x1 = b2f(base[64]), x2 = b2f(base[128]);
    float t0 = x0 + xr0; t0 = (t0 > 0.f) ? t0 : 0.2f * t0; t0 *= at0;
    float t1 = x1 + xr1; t1 = (t1 > 0.f) ? t1 : 0.2f * t1; t1 *= at1;
    float t2 = x2 + xr2; t2 = (t2 > 0.f) ? t2 : 0.2f * t2; t2 *= at2;
#pragma unroll
    for (int d = 32; d > 0; d >>= 1){
      t0 += __shfl_xor(t0, d, 64);
      t1 += __shfl_xor(t1, d, 64);
      t2 += __shfl_xor(t2, d, 64);
    }
    float n0 = fmaxf(mh0, t0), n1 = fmaxf(mh1, t1), n2 = fmaxf(mh2, t2);
    float s0 = __expf(mh0 - n0), s1 = __expf(mh1 - n1), s2 = __expf(mh2 - n2);
    float w0 = __expf(t0 - n0), w1 = __expf(t1 - n1), w2 = __expf(t2 - n2);
    lh0 = lh0 * s0 + w0; ac0 = ac0 * s0 + w0 * x0; mh0 = n0;
    lh1 = lh1 * s1 + w1; ac1 = ac1 * s1 + w1 * x1; mh1 = n1;
    lh2 = lh2 * s2 + w2; ac2 = ac2 * s2 + w2 * x2; mh2 = n2;
  }
  float o0 = ac0 / fmaxf(lh0, 1e-16f);
  float o1 = ac1 / fmaxf(lh1, 1e-16f);
  float o2 = ac2 / fmaxf(lh2, 1e-16f);
  float v = (o0 + o1 + o2) * (1.f / 3.f) + b2f(bias[lane]);
  v = (v > 0.f) ? v : expm1f(v);       // ELU (halves independent => valid on concat)
  if (!(fabsf(v) < 1e30f)) v = 0.f;    // finite-scrub (no-op when healthy)
  aggout[(size_t)wid * 128 + out_off + lane] = f2b(v);
}

// ---------------- h2 = h1 @ W2 + b2 ----------------
__global__ __launch_bounds__(256) void h2_kernel(const u16* __restrict__ AGG,
                                                 const u16* __restrict__ W2, const u16* __restrict__ b2,
                                                 float* __restrict__ H2, void* __restrict__ OUT,
                                                 const int* __restrict__ dflag, int n){
  __shared__ float w2s[128 * 16];
  __shared__ float as_[16][128];
  int isbf = dflag[0];
  int tid = threadIdx.x;
  for (int i = tid; i < 128 * 16; i += 256) w2s[i] = b2f(W2[i]);
  int m0 = blockIdx.x * 16;
  for (int i = tid; i < 16 * 128; i += 256){
    int r = i >> 7, c = i & 127; int m = m0 + r;
    as_[r][c] = (m < n) ? b2f(AGG[(size_t)m * 128 + c]) : 0.f;
  }
  __syncthreads();
  int r = tid >> 4, j = tid & 15;
  int m = m0 + r;
  float acc = b2f(b2[j]);
  for (int k = 0; k < 128; k++) acc += as_[r][k] * w2s[k * 16 + j];
  if (m < n){
    H2[(size_t)m * 16 + j] = acc;
    stout(OUT, (size_t)OFF_H2 + (size_t)m * 16 + j, acc, isbf);
  }
}

// ---------------- Y2 = h2 @ Wcat2 + bcat2 ----------------
__global__ __launch_bounds__(256) void y2_kernel(const float* __restrict__ H2,
                                                 const u16* __restrict__ Wcat2, const u16* __restrict__ bcat2,
                                                 u16* __restrict__ Y2, int n){
  __shared__ u16 ws_[16 * 768];
  __shared__ float h[16][16];
  int tid = threadIdx.x;
  for (int i = tid; i < 16 * 768; i += 256) ws_[i] = Wcat2[i];
  int m0 = blockIdx.x * 16;
  {
    int r = tid >> 4, k = tid & 15; int m = m0 + r;
    h[r][k] = (m < n) ? H2[(size_t)m * 16 + k] : 0.f;
  }
  __syncthreads();
  int j = tid;
  float acc[16][3];
  float bj0 = b2f(bcat2[j]), bj1 = b2f(bcat2[j + 256]), bj2 = b2f(bcat2[j + 512]);
#pragma unroll
  for (int r = 0; r < 16; r++){ acc[r][0] = bj0; acc[r][1] = bj1; acc[r][2] = bj2; }
  for (int k = 0; k < 16; k++){
    float w0 = b2f(ws_[k * 768 + j]);
    float w1 = b2f(ws_[k * 768 + j + 256]);
    float w2 = b2f(ws_[k * 768 + j + 512]);
#pragma unroll
    for (int r = 0; r < 16; r++){
      float hv = h[r][k];
      acc[r][0] += hv * w0; acc[r][1] += hv * w1; acc[r][2] += hv * w2;
    }
  }
#pragma unroll
  for (int r = 0; r < 16; r++){
    int m = m0 + r;
    if (m < n){
      size_t base = (size_t)m * 768;
      Y2[base + j] = f2b(acc[r][0]);
      Y2[base + j + 256] = f2b(acc[r][1]);
      Y2[base + j + 512] = f2b(acc[r][2]);
    }
  }
}

// ---------------- Cross attention ----------------
__global__ __launch_bounds__(256) void cross_attn_kernel(
    const u16* __restrict__ XG, const u16* __restrict__ XS,
    const u16* __restrict__ a1, const u16* __restrict__ a2,
    void* __restrict__ OUT, const int* __restrict__ dflag, int n){
  int m = blockIdx.x;
  int t = threadIdx.x;
  int isbf = dflag[0];
  size_t base = (size_t)m * 256 + t;
  float xg = b2f(XG[base]), xs = b2f(XS[base]);
  if (!(fabsf(xg) < 1e30f)) xg = 0.f;
  if (!(fabsf(xs) < 1e30f)) xs = 0.f;
  float p1 = xg * b2f(a1[t]) + xs * b2f(a1[256 + t]);
  float p2 = xg * b2f(a2[t]) + xs * b2f(a2[256 + t]);
#pragma unroll
  for (int d = 32; d > 0; d >>= 1){
    p1 += __shfl_xor(p1, d, 64);
    p2 += __shfl_xor(p2, d, 64);
  }
  __shared__ float s1[4], s2[4];
  int w = t >> 6, lane = t & 63;
  if (lane == 0){ s1[w] = p1; s2[w] = p2; }
  __syncthreads();
  float e1 = s1[0] + s1[1] + s1[2] + s1[3];
  float e2 = s2[0] + s2[1] + s2[2] + s2[3];
  e1 = (e1 > 0.f) ? e1 : 0.2f * e1;
  e2 = (e2 > 0.f) ? e2 : 0.2f * e2;
  float mx = fmaxf(e1, e2);
  float w1 = __expf(e1 - mx), w2 = __expf(e2 - mx);
  float inv = 1.f / (w1 + w2);
  float l0 = w1 * inv, l1 = w2 * inv;
  stout(OUT, (size_t)OFF_RES + base, l0 * xg + l1 * xs, isbf);
  if (t == 0){
    stout(OUT, (size_t)OFF_LAM + (size_t)m * 2,     l0, isbf);
    stout(OUT, (size_t)OFF_LAM + (size_t)m * 2 + 1, l1, isbf);
  }
}

extern "C" void kernel_launch(void* const* d_in, const int* in_sizes, int n_in,
                              void* d_out, int out_size, void* d_ws, size_t ws_size,
                              hipStream_t stream) {
  const void* gene_freq = d_in[0];   // [256,3000]
  const void* gene_eig  = d_in[1];   // [3000,20000]
  const void* spot_freq = d_in[2];   // [20000,256]
  const void* spot_eig  = d_in[3];   // [256,256]
  const int* net1 = (const int*)d_in[4];
  const int* net2 = (const int*)d_in[5];
  const void *c1_Wl=d_in[6],  *c1_bl=d_in[7],  *c1_Wr=d_in[8],  *c1_br=d_in[9],  *c1_att=d_in[10], *c1_b=d_in[11];
  const void *c1p_Wl=d_in[12],*c1p_bl=d_in[13],*c1p_Wr=d_in[14],*c1p_br=d_in[15],*c1p_att=d_in[16],*c1p_b=d_in[17];
  const void *c3_Wl=d_in[18], *c3_bl=d_in[19], *c3_Wr=d_in[20], *c3_br=d_in[21], *c3_att=d_in[22], *c3_b=d_in[23];
  const void *c3p_Wl=d_in[24],*c3p_bl=d_in[25],*c3p_Wr=d_in[26],*c3p_br=d_in[27],*c3p_att=d_in[28],*c3p_b=d_in[29];
  const void *W2=d_in[30], *b2=d_in[31], *W4=d_in[32], *b4=d_in[33], *a1=d_in[34], *a2=d_in[35];

  // workspace carve (~46 MB), CSR arrays first
  char* p = (char*)d_ws;
  auto carve = [&](size_t bytes) -> char* {
    char* r = p; p += (bytes + 255) & ~(size_t)255; return r;
  };
  int*   flag  = (int*) carve(256);
  int*   cnt1  = (int*) carve((NSPOT + 2) * 4);
  int*   off1  = (int*) carve((NSPOT + 2) * 4);
  int*   cur1  = (int*) carve((NSPOT + 2) * 4);
  int*   srcs1 = (int*) carve((size_t)E1N * 4);
  int*   cnt2  = (int*) carve((NSPOT + 2) * 4);
  int*   off2  = (int*) carve((NSPOT + 2) * 4);
  int*   cur2  = (int*) carve((NSPOT + 2) * 4);
  int*   srcs2 = (int*) carve((size_t)E2N * 4);
  u16*   Wcat1 = (u16*) carve(256 * 768 * 2);
  u16*   bcat1 = (u16*) carve(2048);
  u16*   Wcat2 = (u16*) carve(16 * 768 * 2);
  u16*   bcat2 = (u16*) carve(2048);
  u16*   attc1  = (u16*)carve(192 * 2);
  u16*   attc1p = (u16*)carve(192 * 2);
  u16*   attc3  = (u16*)carve(192 * 2);
  u16*   attc3p = (u16*)carve(192 * 2);
  u16*   bc1  = (u16*)carve(64 * 2);
  u16*   bc1p = (u16*)carve(64 * 2);
  u16*   bc3  = (u16*)carve(64 * 2);
  u16*   bc3p = (u16*)carve(64 * 2);
  u16*   W2c  = (u16*)carve(2048 * 2);
  u16*   b2c  = (u16*)carve(16 * 2);
  u16*   W4c  = (u16*)carve(32768 * 2);
  u16*   b4c  = (u16*)carve(256 * 2);
  u16*   a1c  = (u16*)carve(512 * 2);
  u16*   a2c  = (u16*)carve(512 * 2);
  float* H2   = (float*)carve((size_t)NSPOT * 16 * 4);
  u16*   AGG  = (u16*)  carve((size_t)NSPOT * 128 * 2);
  u16*   Y    = (u16*)  carve((size_t)NSPOT * 768 * 2);   // [xl|xr|xlp|xrp]
  u16*   XG   = Y;                 // alias: Y is dead before Xg/Xs are computed
  u16*   XS   = Y + 5120000;

  // --- dtype sniff ---
  sniff_kernel<<<1, 64, 0, stream>>>((const u16*)spot_freq, flag);

  // --- CSR build ---
  hipMemsetAsync(cnt1, 0, NSPOT * 4, stream);
  hipMemsetAsync(cnt2, 0, NSPOT * 4, stream);
  hist_kernel<<<(E1N + 255) / 256, 256, 0, stream>>>(net1 + E1N, cnt1, E1N);
  hist_kernel<<<(E2N + 255) / 256, 256, 0, stream>>>(net2 + E2N, cnt2, E2N);
  scan_kernel<<<1, 256, 0, stream>>>(cnt1, off1, cur1, NSPOT);
  scan_kernel<<<1, 256, 0, stream>>>(cnt2, off2, cur2, NSPOT);
  scatter_kernel<<<(E1N + 255) / 256, 256, 0, stream>>>(net1, net1 + E1N, cur1, srcs1, E1N);
  scatter_kernel<<<(E2N + 255) / 256, 256, 0, stream>>>(net2, net2 + E2N, cur2, srcs2, E2N);

  // --- small param conversion to bf16 ws ---
  auto conv = [&](const void* s, u16* d, int n){
    conv1d_kernel<<<(n + 255) / 256, 256, 0, stream>>>(s, d, n, flag);
  };
  conv(c1_att, attc1, 192);  conv(c1p_att, attc1p, 192);
  conv(c3_att, attc3, 192);  conv(c3p_att, attc3p, 192);
  conv(c1_b, bc1, 64); conv(c1p_b, bc1p, 64); conv(c3_b, bc3, 64); conv(c3p_b, bc3p, 64);
  conv(W2, W2c, 2048); conv(b2, b2c, 16);
  conv(W4, W4c, 32768); conv(b4, b4c, 256);
  conv(a1, a1c, 512); conv(a2, a2c, 512);

  // --- weight concat ---
  assemble_kernel<<<(256 * 768 + 255) / 256, 256, 0, stream>>>(
      c1_Wl, c1_bl, c1_Wr, c1_br, c1p_Wl, c1p_bl, c1p_Wr, c1p_br, Wcat1, bcat1, 256, flag);
  assemble_kernel<<<(16 * 768 + 255) / 256, 256, 0, stream>>>(
      c3_Wl, c3_bl, c3_Wr, c3_br, c3p_Wl, c3p_bl, c3p_Wr, c3p_br, Wcat2, bcat2, 16, flag);

  // --- layer 1 transforms: Y = spot_freq @ Wcat1 + bcat1 ---
  gemm_mfma<false, false, true, false, false, true, false><<<dim3(12, 157), 256, 0, stream>>>(
      spot_freq, Wcat1, bcat1, Y, flag, 0, 0, NSPOT, 768, 256, 256, 768, 768);

  // --- layer 1 GAT ---
  gat_kernel<<<5000, 256, 0, stream>>>(Y, 0,   192, off1, srcs1, attc1,  bc1,  AGG, 0,  NSPOT, E1N);
  gat_kernel<<<5000, 256, 0, stream>>>(Y, 384, 576, off2, srcs2, attc1p, bc1p, AGG, 64, NSPOT, E2N);

  // --- h2 ---
  h2_kernel<<<1250, 256, 0, stream>>>(AGG, W2c, b2c, H2, d_out, flag, NSPOT);

  // --- layer 2 transforms ---
  y2_kernel<<<1250, 256, 0, stream>>>(H2, Wcat2, bcat2, Y, NSPOT);

  // --- layer 2 GAT ---
  gat_kernel<<<5000, 256, 0, stream>>>(Y, 0,   192, off1, srcs1, attc3,  bc3,  AGG, 0,  NSPOT, E1N);
  gat_kernel<<<5000, 256, 0, stream>>>(Y, 384, 576, off2, srcs2, attc3p, bc3p, AGG, 64, NSPOT, E2N);

  // --- h4 = h3 @ W4 + b4 -> d_out[OFF_H4] (dtype per flag) ---
  gemm_mfma<false, false, false, false, false, true, true><<<dim3(4, 157), 256, 0, stream>>>(
      AGG, W4c, b4c, d_out, flag, 0, OFF_H4, NSPOT, 256, 128, 128, 256, 256);

  // --- Xs = relu(h4 @ spot_eig) -> bf16 ws (aliases dead Y) ---
  gemm_mfma<false, false, true, true, true, false, false><<<dim3(4, 157), 256, 0, stream>>>(
      d_out, spot_eig, nullptr, XS, flag, OFF_H4, 0, NSPOT, 256, 256, 256, 256, 256);

  // --- Xg = relu(gene_eig^T @ gene_freq^T) -> bf16 ws ---
  gemm_mfma<true, true, true, true, true, false, false><<<dim3(4, 157), 256, 0, stream>>>(
      gene_eig, gene_freq, nullptr, XG, flag, 0, 0, NSPOT, 256, NGENE, NSPOT, NGENE, 256);

  // --- cross attention ---
  cross_attn_kernel<<<NSPOT, 256, 0, stream>>>(XG, XS, a1c, a2c, d_out, flag, NSPOT);

  (void)in_sizes; (void)n_in; (void)out_size; (void)ws_size;
}

// Round 3
// 1364.704 us; speedup vs baseline: 1.0846x; 1.0846x over previous
//
#include <hip/hip_runtime.h>

typedef unsigned short u16;
typedef __attribute__((ext_vector_type(8))) short bf16x8;   // 8 x bf16 bits
typedef __attribute__((ext_vector_type(4))) float floatx4;

#define NSPOT 20000
#define NGENE 3000
#define E1N   640000
#define E2N   320000

// output element offsets (res, lam, h2, h4 concatenated)
#define OFF_RES 0
#define OFF_LAM 5120000
#define OFF_H2  5160000
#define OFF_H4  5480000

__device__ __forceinline__ float b2f(u16 u){
  union { unsigned int i; float f; } v; v.i = ((unsigned int)u) << 16; return v.f;
}
__device__ __forceinline__ u16 f2b(float f){
  union { float f; unsigned int i; } v; v.f = f;
  unsigned int i = v.i;
  return (u16)((i + 0x7FFFu + ((i >> 16) & 1u)) >> 16);
}
__device__ __forceinline__ void stout(void* O, size_t i, float v, int isbf){
  if (isbf) ((u16*)O)[i] = f2b(v); else ((float*)O)[i] = v;
}
__device__ __forceinline__ u16 ldu(const void* p, size_t i, int isbf){
  return isbf ? ((const u16*)p)[i] : f2b(((const float*)p)[i]);
}

// ---------------- dtype sniffer ----------------
__global__ void sniff_kernel(const u16* __restrict__ x, int* __restrict__ flag){
  int lane = threadIdx.x;
  u16 u = x[lane * 2];
  int e = (u >> 7) & 0xFF;
  int sane = (u == 0) || (e >= 0x60 && e <= 0xA0);
  unsigned long long b = __ballot(sane);
  if (lane == 0) flag[0] = (__popcll(b) >= 48) ? 1 : 0;
}

// ---------------- batched small-param convert ----------------
struct ConvSeg { const void* src; u16* dst; int n; };
struct ConvBatch { ConvSeg s[14]; };
__global__ void convbatch_kernel(ConvBatch cb, const int* __restrict__ dflag){
  ConvSeg S = cb.s[blockIdx.y];
  int i = blockIdx.x * 256 + threadIdx.x;
  if (i < S.n) S.dst[i] = ldu(S.src, i, dflag[0]);
}

// vectorized convert (n multiple of 4)
__global__ void conv4_kernel(const void* __restrict__ src, u16* __restrict__ dst, int n4,
                             const int* __restrict__ dflag){
  int i = blockIdx.x * 256 + threadIdx.x;
  if (i >= n4) return;
  size_t b = (size_t)i * 4;
  u16 o[4];
  if (dflag[0]){
    *(uint2*)o = *(const uint2*)((const u16*)src + b);
  } else {
    float4 f = *(const float4*)((const float*)src + b);
    o[0]=f2b(f.x); o[1]=f2b(f.y); o[2]=f2b(f.z); o[3]=f2b(f.w);
  }
  *(uint2*)(dst + b) = *(uint2*)o;
}

// ---------------- transpose GE[K][M] -> AT[M][K] bf16 (K%8==0 rows, guards inside) ----
__global__ __launch_bounds__(256) void transpose_kernel(
    const void* __restrict__ GE, u16* __restrict__ AT,
    const int* __restrict__ dflag, int K, int M){
  __shared__ float tile[64 * 65];
  int isbf = dflag[0];
  int m0 = blockIdx.x * 64, k0 = blockIdx.y * 64;
#pragma unroll
  for (int i = 0; i < 4; i++){
    int idx = threadIdx.x + i * 256;
    int kr = idx >> 4, mc = (idx & 15) * 4;
    int gk = k0 + kr, gm = m0 + mc;
    if (gk < K){
      float v0 = 0.f, v1 = 0.f, v2 = 0.f, v3 = 0.f;
      if (gm + 4 <= M){
        if (isbf){
          const u16* pp = (const u16*)GE + (size_t)gk * M + gm;
          v0 = b2f(pp[0]); v1 = b2f(pp[1]); v2 = b2f(pp[2]); v3 = b2f(pp[3]);
        } else {
          float4 f = *(const float4*)((const float*)GE + (size_t)gk * M + gm);
          v0 = f.x; v1 = f.y; v2 = f.z; v3 = f.w;
        }
      } else {
        for (int e = 0; e < 4; e++){
          if (gm + e < M){
            float t = isbf ? b2f(((const u16*)GE)[(size_t)gk * M + gm + e])
                           : ((const float*)GE)[(size_t)gk * M + gm + e];
            if (e == 0) v0 = t; else if (e == 1) v1 = t; else if (e == 2) v2 = t; else v3 = t;
          }
        }
      }
      tile[(mc + 0) * 65 + kr] = v0;
      tile[(mc + 1) * 65 + kr] = v1;
      tile[(mc + 2) * 65 + kr] = v2;
      tile[(mc + 3) * 65 + kr] = v3;
    }
  }
  __syncthreads();
#pragma unroll
  for (int i = 0; i < 2; i++){
    int idx = threadIdx.x + i * 256;
    int mr = idx >> 3, kc = (idx & 7) * 8;
    int gm = m0 + mr, gk = k0 + kc;
    if (gm < M && gk < K){
      if (gk + 8 <= K){
        u16 o[8];
#pragma unroll
        for (int e = 0; e < 8; e++) o[e] = f2b(tile[mr * 65 + kc + e]);
        *(uint4*)&AT[(size_t)gm * K + gk] = *(uint4*)o;
      } else {
        for (int e = 0; e < 8 && gk + e < K; e++)
          AT[(size_t)gm * K + gk + e] = f2b(tile[mr * 65 + kc + e]);
      }
    }
  }
}

// ---------------- CSR build ----------------
__global__ void hist_kernel(const int* __restrict__ dst, int* __restrict__ cnt, int E){
  int e = blockIdx.x * 256 + threadIdx.x;
  if (e < E){ int d = dst[e]; if ((unsigned)d < (unsigned)NSPOT) atomicAdd(&cnt[d], 1); }
}

__global__ void scan_kernel(const int* __restrict__ cnt, int* __restrict__ off,
                            int* __restrict__ cur, int n){
  __shared__ int part[256];
  int tid = threadIdx.x;
  int chunk = (n + 255) / 256;
  int lo = tid * chunk; if (lo > n) lo = n;
  int hi = lo + chunk; if (hi > n) hi = n;
  int s = 0;
  for (int i = lo; i < hi; i++) s += cnt[i];
  part[tid] = s;
  __syncthreads();
  if (tid == 0){
    int run = 0;
    for (int i = 0; i < 256; i++){ int t = part[i]; part[i] = run; run += t; }
  }
  __syncthreads();
  int run = part[tid];
  for (int i = lo; i < hi; i++){ off[i] = run; cur[i] = run; run += cnt[i]; }
  if (hi == n) off[n] = run;
}

__global__ void scatter_kernel(const int* __restrict__ src, const int* __restrict__ dst,
                               int* __restrict__ cur, int* __restrict__ out, int E){
  int e = blockIdx.x * 256 + threadIdx.x;
  if (e < E){
    int d = dst[e];
    if ((unsigned)d < (unsigned)NSPOT){
      int p = atomicAdd(&cur[d], 1);
      if ((unsigned)p < (unsigned)E) out[p] = src[e];
    }
  }
}

// ---------------- weight concat ----------------
__global__ void assemble_kernel(const void* Wl, const void* bl, const void* Wr, const void* br,
                                const void* Wlp, const void* blp, const void* Wrp, const void* brp,
                                u16* __restrict__ Wcat, u16* __restrict__ bcat, int Kdim,
                                const int* __restrict__ dflag){
  int isbf = dflag[0];
  int idx = blockIdx.x * 256 + threadIdx.x;
  int total = Kdim * 768;
  if (idx < total){
    int k = idx / 768, j = idx % 768;
    int seg = j / 192, jj = j % 192;
    const void* W = (seg == 0) ? Wl : (seg == 1) ? Wr : (seg == 2) ? Wlp : Wrp;
    Wcat[idx] = ldu(W, (size_t)k * 192 + jj, isbf);
  }
  if (idx < 768){
    int seg = idx / 192, jj = idx % 192;
    const void* b = (seg == 0) ? bl : (seg == 1) ? br : (seg == 2) ? blp : brp;
    bcat[idx] = ldu(b, jj, isbf);
  }
}

// ---------------- MFMA GEMM (BM = 64*BMI, BN=64) ----------------
template<int BMI, bool A_KM, bool B_NK, bool A_EXT, bool B_EXT, bool RELU, bool HAS_BIAS, bool C_OUT>
__global__ __launch_bounds__(256) void gemm_mfma(
    const void* __restrict__ A, const void* __restrict__ B,
    const u16* __restrict__ bias, void* __restrict__ Cp,
    const int* __restrict__ dflag, size_t aoff, size_t coff,
    int M, int N, int K, int lda, int ldb, int ldc)
{
  const int isbf = dflag[0];
  constexpr int BM = 64 * BMI, BK = 32, LDA = BK + 8, LDB = BK + 8;
  __shared__ __align__(16) u16 As[BM * LDA];
  __shared__ __align__(16) u16 Bs[64 * LDB];
  const u16*   A16 = (const u16*)A + aoff;
  const float* A32 = (const float*)A + aoff;
  const u16*   B16 = (const u16*)B;
  const float* B32 = (const float*)B;
  auto ldA = [&](size_t i) -> u16 { return (!A_EXT || isbf) ? A16[i] : f2b(A32[i]); };
  auto ldB = [&](size_t i) -> u16 { return (!B_EXT || isbf) ? B16[i] : f2b(B32[i]); };

  int tid = threadIdx.x;
  int lane = tid & 63, w = tid >> 6;
  int m0 = blockIdx.y * BM, n0 = blockIdx.x * 64;
  floatx4 acc[BMI][4] = {};
  int quad = lane >> 4;
  int nk = (K + BK - 1) / BK;
  for (int kt = 0; kt < nk; kt++){
    int k0 = kt * BK;
    // ---- stage A -> As[m][k] ----
    if (!A_KM){
#pragma unroll
      for (int i = 0; i < BMI; i++){
        int id = tid + i * 256;
        int r = id >> 2, c = (id & 3) * 8;
        int gm = m0 + r, gk = k0 + c;
        if (gm < M && gk + 8 <= K){
          if (!A_EXT || isbf){
            *(uint4*)&As[r * LDA + c] = *(const uint4*)(A16 + (size_t)gm * lda + gk);
          } else {
            const float* p = A32 + (size_t)gm * lda + gk;
            float4 f0 = *(const float4*)p, f1 = *(const float4*)(p + 4);
            u16* d = &As[r * LDA + c];
            d[0]=f2b(f0.x); d[1]=f2b(f0.y); d[2]=f2b(f0.z); d[3]=f2b(f0.w);
            d[4]=f2b(f1.x); d[5]=f2b(f1.y); d[6]=f2b(f1.z); d[7]=f2b(f1.w);
          }
        } else {
          for (int e = 0; e < 8; e++)
            As[r * LDA + c + e] = (gm < M && gk + e < K) ? ldA((size_t)gm * lda + gk + e) : (u16)0;
        }
      }
    } else {
#pragma unroll
      for (int i = 0; i < BMI; i++){
        int id = tid + i * 256;
        int kk, rr;
        if (BMI == 2){ kk = id >> 4; rr = (id & 15) * 8; }
        else         { kk = id >> 3; rr = (id & 7) * 8; }
        int gk = k0 + kk, gm = m0 + rr;
        if (gk < K && gm + 8 <= M){
          if (!A_EXT || isbf){
            uint4 v = *(const uint4*)(A16 + (size_t)gk * lda + gm);
            const u16* pv = (const u16*)&v;
#pragma unroll
            for (int e = 0; e < 8; e++) As[(rr + e) * LDA + kk] = pv[e];
          } else {
            const float* p = A32 + (size_t)gk * lda + gm;
            float4 f0 = *(const float4*)p, f1 = *(const float4*)(p + 4);
            As[(rr+0)*LDA+kk]=f2b(f0.x); As[(rr+1)*LDA+kk]=f2b(f0.y);
            As[(rr+2)*LDA+kk]=f2b(f0.z); As[(rr+3)*LDA+kk]=f2b(f0.w);
            As[(rr+4)*LDA+kk]=f2b(f1.x); As[(rr+5)*LDA+kk]=f2b(f1.y);
            As[(rr+6)*LDA+kk]=f2b(f1.z); As[(rr+7)*LDA+kk]=f2b(f1.w);
          }
        } else {
          for (int e = 0; e < 8; e++)
            As[(rr + e) * LDA + kk] = (gk < K && gm + e < M) ? ldA((size_t)gk * lda + gm + e) : (u16)0;
        }
      }
    }
    // ---- stage B -> Bs[n][k] ----
    if (B_NK){
      int r = tid >> 2, c = (tid & 3) * 8;
      int gn = n0 + r, gk = k0 + c;
      if (gn < N && gk + 8 <= K){
        if (!B_EXT || isbf){
          *(uint4*)&Bs[r * LDB + c] = *(const uint4*)(B16 + (size_t)gn * ldb + gk);
        } else {
          const float* p = B32 + (size_t)gn * ldb + gk;
          float4 f0 = *(const float4*)p, f1 = *(const float4*)(p + 4);
          u16* d = &Bs[r * LDB + c];
          d[0]=f2b(f0.x); d[1]=f2b(f0.y); d[2]=f2b(f0.z); d[3]=f2b(f0.w);
          d[4]=f2b(f1.x); d[5]=f2b(f1.y); d[6]=f2b(f1.z); d[7]=f2b(f1.w);
        }
      } else {
        for (int e = 0; e < 8; e++)
          Bs[r * LDB + c + e] = (gn < N && gk + e < K) ? ldB((size_t)gn * ldb + gk + e) : (u16)0;
      }
    } else {
      int kk = tid >> 3, nn = (tid & 7) * 8;
      int gk = k0 + kk, gn = n0 + nn;
      if (gk < K && gn + 8 <= N){
        if (!B_EXT || isbf){
          uint4 v = *(const uint4*)(B16 + (size_t)gk * ldb + gn);
          const u16* pv = (const u16*)&v;
#pragma unroll
          for (int e = 0; e < 8; e++) Bs[(nn + e) * LDB + kk] = pv[e];
        } else {
          const float* p = B32 + (size_t)gk * ldb + gn;
          float4 f0 = *(const float4*)p, f1 = *(const float4*)(p + 4);
          Bs[(nn+0)*LDB+kk]=f2b(f0.x); Bs[(nn+1)*LDB+kk]=f2b(f0.y);
          Bs[(nn+2)*LDB+kk]=f2b(f0.z); Bs[(nn+3)*LDB+kk]=f2b(f0.w);
          Bs[(nn+4)*LDB+kk]=f2b(f1.x); Bs[(nn+5)*LDB+kk]=f2b(f1.y);
          Bs[(nn+6)*LDB+kk]=f2b(f1.z); Bs[(nn+7)*LDB+kk]=f2b(f1.w);
        }
      } else {
        for (int e = 0; e < 8; e++)
          Bs[(nn + e) * LDB + kk] = (gk < K && gn + e < N) ? ldB((size_t)gk * ldb + gn + e) : (u16)0;
      }
    }
    __syncthreads();
    // ---- MFMA ----
    bf16x8 af[BMI];
#pragma unroll
    for (int mi = 0; mi < BMI; mi++)
      af[mi] = *(const bf16x8*)&As[(w * (16 * BMI) + mi * 16 + (lane & 15)) * LDA + quad * 8];
#pragma unroll
    for (int ni = 0; ni < 4; ni++){
      bf16x8 bfr = *(const bf16x8*)&Bs[(ni * 16 + (lane & 15)) * LDB + quad * 8];
#pragma unroll
      for (int mi = 0; mi < BMI; mi++)
        acc[mi][ni] = __builtin_amdgcn_mfma_f32_16x16x32_bf16(af[mi], bfr, acc[mi][ni], 0, 0, 0);
    }
    __syncthreads();
  }
  // ---- epilogue ----
#pragma unroll
  for (int mi = 0; mi < BMI; mi++)
#pragma unroll
    for (int ni = 0; ni < 4; ni++)
#pragma unroll
      for (int r = 0; r < 4; r++){
        int row = m0 + w * (16 * BMI) + mi * 16 + quad * 4 + r;
        int col = n0 + ni * 16 + (lane & 15);
        if (row < M && col < N){
          float v = acc[mi][ni][r];
          if (HAS_BIAS) v += b2f(bias[col]);
          if (RELU) v = fmaxf(v, 0.f);
          size_t ci = coff + (size_t)row * ldc + col;
          if (!C_OUT) ((u16*)Cp)[ci] = f2b(v);
          else stout(Cp, ci, v, isbf);
        }
      }
}

// ---------------- GATv2 aggregation: one wave per dst, online softmax, prefetch ----------------
__global__ __launch_bounds__(256) void gat_kernel(
    const u16* __restrict__ Y, int xl_off, int xr_off,
    const int* __restrict__ off, const int* __restrict__ srcs,
    const u16* __restrict__ att, const u16* __restrict__ bias,
    u16* __restrict__ aggout, int out_off, int n, int E)
{
  int wid = (blockIdx.x * 256 + threadIdx.x) >> 6;
  int lane = threadIdx.x & 63;
  if (wid >= n) return;
  const int ldY = 768;
  size_t drow = (size_t)wid * ldY;
  float xr0 = b2f(Y[drow + xr_off + lane]);
  float xr1 = b2f(Y[drow + xr_off + 64 + lane]);
  float xr2 = b2f(Y[drow + xr_off + 128 + lane]);
  float at0 = b2f(att[lane]), at1 = b2f(att[64 + lane]), at2 = b2f(att[128 + lane]);
  float mh0 = -INFINITY, mh1 = -INFINITY, mh2 = -INFINITY;
  float lh0 = 0.f, lh1 = 0.f, lh2 = 0.f;
  float ac0 = 0.f, ac1 = 0.f, ac2 = 0.f;
  int beg = off[wid], end = off[wid + 1];
  beg = max(0, min(beg, E));
  end = max(beg, min(end, E));
  float nx0 = 0.f, nx1 = 0.f, nx2 = 0.f;
  if (beg < end){
    int s = srcs[beg];
    if ((unsigned)s >= (unsigned)NSPOT) s = 0;
    const u16* b = Y + (size_t)s * ldY + xl_off + lane;
    nx0 = b2f(b[0]); nx1 = b2f(b[64]); nx2 = b2f(b[128]);
  }
  for (int i = beg; i < end; i++){
    float x0 = nx0, x1 = nx1, x2 = nx2;
    if (i + 1 < end){
      int s = srcs[i + 1];
      if ((unsigned)s >= (unsigned)NSPOT) s = 0;
      const u16* b = Y + (size_t)s * ldY + xl_off + lane;
      nx0 = b2f(b[0]); nx1 = b2f(b[64]); nx2 = b2f(b[128]);
    }
    float t0 = x0 + xr0; t0 = (t0 > 0.f) ? t0 : 0.2f * t0; t0 *= at0;
    float t1 = x1 + xr1; t1 = (t1 > 0.f) ? t1 : 0.2f * t1; t1 *= at1;
    float t2 = x2 + xr2; t2 = (t2 > 0.f) ? t2 : 0.2f * t2; t2 *= at2;
#pragma unroll
    for (int d = 32; d > 0; d >>= 1){
      t0 += __shfl_xor(t0, d, 64);
      t1 += __shfl_xor(t1, d, 64);
      t2 += __shfl_xor(t2, d, 64);
    }
    float n0 = fmaxf(mh0, t0), n1 = fmaxf(mh1, t1), n2 = fmaxf(mh2, t2);
    float s0 = __expf(mh0 - n0), s1 = __expf(mh1 - n1), s2 = __expf(mh2 - n2);
    float w0 = __expf(t0 - n0), w1 = __expf(t1 - n1), w2 = __expf(t2 - n2);
    lh0 = lh0 * s0 + w0; ac0 = ac0 * s0 + w0 * x0; mh0 = n0;
    lh1 = lh1 * s1 + w1; ac1 = ac1 * s1 + w1 * x1; mh1 = n1;
    lh2 = lh2 * s2 + w2; ac2 = ac2 * s2 + w2 * x2; mh2 = n2;
  }
  float o0 = ac0 / fmaxf(lh0, 1e-16f);
  float o1 = ac1 / fmaxf(lh1, 1e-16f);
  float o2 = ac2 / fmaxf(lh2, 1e-16f);
  float v = (o0 + o1 + o2) * (1.f / 3.f) + b2f(bias[lane]);
  v = (v > 0.f) ? v : expm1f(v);
  if (!(fabsf(v) < 1e30f)) v = 0.f;
  aggout[(size_t)wid * 128 + out_off + lane] = f2b(v);
}

// ---------------- h2 = h1 @ W2 + b2 ----------------
__global__ __launch_bounds__(256) void h2_kernel(const u16* __restrict__ AGG,
                                                 const u16* __restrict__ W2, const u16* __restrict__ b2,
                                                 float* __restrict__ H2, void* __restrict__ OUT,
                                                 const int* __restrict__ dflag, int n){
  __shared__ float w2s[128 * 16];
  __shared__ float as_[16][128];
  int isbf = dflag[0];
  int tid = threadIdx.x;
  for (int i = tid; i < 128 * 16; i += 256) w2s[i] = b2f(W2[i]);
  int m0 = blockIdx.x * 16;
  for (int i = tid; i < 16 * 128; i += 256){
    int r = i >> 7, c = i & 127; int m = m0 + r;
    as_[r][c] = (m < n) ? b2f(AGG[(size_t)m * 128 + c]) : 0.f;
  }
  __syncthreads();
  int r = tid >> 4, j = tid & 15;
  int m = m0 + r;
  float acc = b2f(b2[j]);
  for (int k = 0; k < 128; k++) acc += as_[r][k] * w2s[k * 16 + j];
  if (m < n){
    H2[(size_t)m * 16 + j] = acc;
    stout(OUT, (size_t)OFF_H2 + (size_t)m * 16 + j, acc, isbf);
  }
}

// ---------------- Y2 = h2 @ Wcat2 + bcat2 ----------------
__global__ __launch_bounds__(256) void y2_kernel(const float* __restrict__ H2,
                                                 const u16* __restrict__ Wcat2, const u16* __restrict__ bcat2,
                                                 u16* __restrict__ Y2, int n){
  __shared__ u16 ws_[16 * 768];
  __shared__ float h[16][16];
  int tid = threadIdx.x;
  for (int i = tid; i < 16 * 768; i += 256) ws_[i] = Wcat2[i];
  int m0 = blockIdx.x * 16;
  {
    int r = tid >> 4, k = tid & 15; int m = m0 + r;
    h[r][k] = (m < n) ? H2[(size_t)m * 16 + k] : 0.f;
  }
  __syncthreads();
  int j = tid;
  float acc[16][3];
  float bj0 = b2f(bcat2[j]), bj1 = b2f(bcat2[j + 256]), bj2 = b2f(bcat2[j + 512]);
#pragma unroll
  for (int r = 0; r < 16; r++){ acc[r][0] = bj0; acc[r][1] = bj1; acc[r][2] = bj2; }
  for (int k = 0; k < 16; k++){
    float w0 = b2f(ws_[k * 768 + j]);
    float w1 = b2f(ws_[k * 768 + j + 256]);
    float w2 = b2f(ws_[k * 768 + j + 512]);
#pragma unroll
    for (int r = 0; r < 16; r++){
      float hv = h[r][k];
      acc[r][0] += hv * w0; acc[r][1] += hv * w1; acc[r][2] += hv * w2;
    }
  }
#pragma unroll
  for (int r = 0; r < 16; r++){
    int m = m0 + r;
    if (m < n){
      size_t base = (size_t)m * 768;
      Y2[base + j] = f2b(acc[r][0]);
      Y2[base + j + 256] = f2b(acc[r][1]);
      Y2[base + j + 512] = f2b(acc[r][2]);
    }
  }
}

// ---------------- Cross attention (wave per row) ----------------
__global__ __launch_bounds__(256) void cross_attn_kernel(
    const u16* __restrict__ XG, const u16* __restrict__ XS,
    const u16* __restrict__ a1, const u16* __restrict__ a2,
    void* __restrict__ OUT, const int* __restrict__ dflag, int n){
  int wid = (blockIdx.x * 256 + threadIdx.x) >> 6;
  int lane = threadIdx.x & 63;
  if (wid >= n) return;
  int isbf = dflag[0];
  int c0 = lane * 4;
  size_t base = (size_t)wid * 256 + c0;
  float g[4], s[4];
#pragma unroll
  for (int e = 0; e < 4; e++){ g[e] = b2f(XG[base + e]); s[e] = b2f(XS[base + e]); }
  float p1 = 0.f, p2 = 0.f;
#pragma unroll
  for (int e = 0; e < 4; e++){
    p1 += g[e] * b2f(a1[c0 + e]) + s[e] * b2f(a1[256 + c0 + e]);
    p2 += g[e] * b2f(a2[c0 + e]) + s[e] * b2f(a2[256 + c0 + e]);
  }
#pragma unroll
  for (int d = 32; d > 0; d >>= 1){
    p1 += __shfl_xor(p1, d, 64);
    p2 += __shfl_xor(p2, d, 64);
  }
  float e1 = (p1 > 0.f) ? p1 : 0.2f * p1;
  float e2 = (p2 > 0.f) ? p2 : 0.2f * p2;
  float mx = fmaxf(e1, e2);
  float w1 = __expf(e1 - mx), w2 = __expf(e2 - mx);
  float inv = 1.f / (w1 + w2);
  float l0 = w1 * inv, l1 = w2 * inv;
#pragma unroll
  for (int e = 0; e < 4; e++)
    stout(OUT, (size_t)OFF_RES + base + e, l0 * g[e] + l1 * s[e], isbf);
  if (lane == 0){
    stout(OUT, (size_t)OFF_LAM + (size_t)wid * 2,     l0, isbf);
    stout(OUT, (size_t)OFF_LAM + (size_t)wid * 2 + 1, l1, isbf);
  }
}

extern "C" void kernel_launch(void* const* d_in, const int* in_sizes, int n_in,
                              void* d_out, int out_size, void* d_ws, size_t ws_size,
                              hipStream_t stream) {
  const void* gene_freq = d_in[0];
  const void* gene_eig  = d_in[1];
  const void* spot_freq = d_in[2];
  const void* spot_eig  = d_in[3];
  const int* net1 = (const int*)d_in[4];
  const int* net2 = (const int*)d_in[5];
  const void *c1_Wl=d_in[6],  *c1_bl=d_in[7],  *c1_Wr=d_in[8],  *c1_br=d_in[9],  *c1_att=d_in[10], *c1_b=d_in[11];
  const void *c1p_Wl=d_in[12],*c1p_bl=d_in[13],*c1p_Wr=d_in[14],*c1p_br=d_in[15],*c1p_att=d_in[16],*c1p_b=d_in[17];
  const void *c3_Wl=d_in[18], *c3_bl=d_in[19], *c3_Wr=d_in[20], *c3_br=d_in[21], *c3_att=d_in[22], *c3_b=d_in[23];
  const void *c3p_Wl=d_in[24],*c3p_bl=d_in[25],*c3p_Wr=d_in[26],*c3p_br=d_in[27],*c3p_att=d_in[28],*c3p_b=d_in[29];
  const void *W2=d_in[30], *b2=d_in[31], *W4=d_in[32], *b4=d_in[33], *a1=d_in[34], *a2=d_in[35];

  // ---- workspace carve: common area then region R ----
  char* p0 = (char*)d_ws;
  char* p = p0;
  auto carve = [&](size_t bytes) -> char* {
    char* r = p; p += (bytes + 255) & ~(size_t)255; return r;
  };
  int*   flag  = (int*) carve(256);
  int*   cnt1  = (int*) carve((NSPOT + 2) * 4);
  int*   off1  = (int*) carve((NSPOT + 2) * 4);
  int*   cur1  = (int*) carve((NSPOT + 2) * 4);
  int*   srcs1 = (int*) carve((size_t)E1N * 4);
  int*   cnt2  = (int*) carve((NSPOT + 2) * 4);
  int*   off2  = (int*) carve((NSPOT + 2) * 4);
  int*   cur2  = (int*) carve((NSPOT + 2) * 4);
  int*   srcs2 = (int*) carve((size_t)E2N * 4);
  u16*   Wcat1 = (u16*) carve(256 * 768 * 2);
  u16*   bcat1 = (u16*) carve(2048);
  u16*   Wcat2 = (u16*) carve(16 * 768 * 2);
  u16*   bcat2 = (u16*) carve(2048);
  u16*   attc1  = (u16*)carve(192 * 2);
  u16*   attc1p = (u16*)carve(192 * 2);
  u16*   attc3  = (u16*)carve(192 * 2);
  u16*   attc3p = (u16*)carve(192 * 2);
  u16*   bc1  = (u16*)carve(64 * 2);
  u16*   bc1p = (u16*)carve(64 * 2);
  u16*   bc3  = (u16*)carve(64 * 2);
  u16*   bc3p = (u16*)carve(64 * 2);
  u16*   W2c  = (u16*)carve(2048 * 2);
  u16*   b2c  = (u16*)carve(16 * 2);
  u16*   W4c  = (u16*)carve(32768 * 2);
  u16*   b4c  = (u16*)carve(256 * 2);
  u16*   a1c  = (u16*)carve(512 * 2);
  u16*   a2c  = (u16*)carve(512 * 2);
  u16*   GF16 = (u16*) carve((size_t)256 * 3000 * 2);
  u16*   SE16 = (u16*) carve((size_t)256 * 256 * 2);
  float* H2   = (float*)carve((size_t)NSPOT * 16 * 4);
  u16*   AGG  = (u16*)  carve((size_t)NSPOT * 128 * 2);
  u16*   XGp  = (u16*)  carve((size_t)NSPOT * 256 * 2);   // persistent XG (plan A)
  char*  R    = carve(0);                                  // region start
  size_t used_common = (size_t)(R - p0);
  size_t needA = used_common + (size_t)NSPOT * NGENE * 2 + 4096;
  bool planA = (ws_size >= needA);

  // --- common prologue ---
  sniff_kernel<<<1, 64, 0, stream>>>((const u16*)spot_freq, flag);
  hipMemsetAsync(cnt1, 0, NSPOT * 4, stream);
  hipMemsetAsync(cnt2, 0, NSPOT * 4, stream);
  hist_kernel<<<(E1N + 255) / 256, 256, 0, stream>>>(net1 + E1N, cnt1, E1N);
  hist_kernel<<<(E2N + 255) / 256, 256, 0, stream>>>(net2 + E2N, cnt2, E2N);
  scan_kernel<<<1, 256, 0, stream>>>(cnt1, off1, cur1, NSPOT);
  scan_kernel<<<1, 256, 0, stream>>>(cnt2, off2, cur2, NSPOT);
  scatter_kernel<<<(E1N + 255) / 256, 256, 0, stream>>>(net1, net1 + E1N, cur1, srcs1, E1N);
  scatter_kernel<<<(E2N + 255) / 256, 256, 0, stream>>>(net2, net2 + E2N, cur2, srcs2, E2N);

  ConvBatch cb;
  cb.s[0]  = {c1_att,  attc1,  192}; cb.s[1]  = {c1p_att, attc1p, 192};
  cb.s[2]  = {c3_att,  attc3,  192}; cb.s[3]  = {c3p_att, attc3p, 192};
  cb.s[4]  = {c1_b, bc1, 64}; cb.s[5]  = {c1p_b, bc1p, 64};
  cb.s[6]  = {c3_b, bc3, 64}; cb.s[7]  = {c3p_b, bc3p, 64};
  cb.s[8]  = {W2, W2c, 2048}; cb.s[9]  = {b2, b2c, 16};
  cb.s[10] = {W4, W4c, 32768}; cb.s[11] = {b4, b4c, 256};
  cb.s[12] = {a1, a1c, 512}; cb.s[13] = {a2, a2c, 512};
  convbatch_kernel<<<dim3(128, 14), 256, 0, stream>>>(cb, flag);
  conv4_kernel<<<(256 * 3000 / 4 + 255) / 256, 256, 0, stream>>>(gene_freq, GF16, 256 * 3000 / 4, flag);
  conv4_kernel<<<(256 * 256 / 4 + 255) / 256, 256, 0, stream>>>(spot_eig, SE16, 256 * 256 / 4, flag);

  assemble_kernel<<<(256 * 768 + 255) / 256, 256, 0, stream>>>(
      c1_Wl, c1_bl, c1_Wr, c1_br, c1p_Wl, c1p_bl, c1p_Wr, c1p_br, Wcat1, bcat1, 256, flag);
  assemble_kernel<<<(16 * 768 + 255) / 256, 256, 0, stream>>>(
      c3_Wl, c3_bl, c3_Wr, c3_br, c3p_Wl, c3p_bl, c3p_Wr, c3p_br, Wcat2, bcat2, 16, flag);

  if (planA){
    u16* AT   = (u16*)R;                              // [20000][3000], dead after Xg
    u16* SF16 = (u16*)R;                              // reuse R after Xg
    u16* Y    = (u16*)(R + 10485760);                 // [20000][768]
    u16* XS   = (u16*)(R + 10485760 + 31457280);      // [20000][256]
    u16* XG   = XGp;

    // transpose gene_eig [3000][20000] -> AT [20000][3000] bf16
    transpose_kernel<<<dim3(313, 47), 256, 0, stream>>>(gene_eig, AT, flag, NGENE, NSPOT);
    // Xg = relu(AT @ GF16^T)  M=20000 N=256 K=3000
    gemm_mfma<1, false, true, false, false, true, false, false><<<dim3(4, 313), 256, 0, stream>>>(
        AT, GF16, nullptr, XG, flag, 0, 0, NSPOT, 256, NGENE, NGENE, NGENE, 256);
    // spot_freq -> bf16 (into R, AT now dead)
    conv4_kernel<<<(NSPOT * 256 / 4 + 255) / 256, 256, 0, stream>>>(spot_freq, SF16, NSPOT * 256 / 4, flag);
    // Y = SF16 @ Wcat1 + bcat1  M=20000 N=768 K=256
    gemm_mfma<2, false, false, false, false, false, true, false><<<dim3(12, 157), 256, 0, stream>>>(
        SF16, Wcat1, bcat1, Y, flag, 0, 0, NSPOT, 768, 256, 256, 768, 768);
    // layer 1 GAT
    gat_kernel<<<5000, 256, 0, stream>>>(Y, 0,   192, off1, srcs1, attc1,  bc1,  AGG, 0,  NSPOT, E1N);
    gat_kernel<<<5000, 256, 0, stream>>>(Y, 384, 576, off2, srcs2, attc1p, bc1p, AGG, 64, NSPOT, E2N);
    h2_kernel<<<1250, 256, 0, stream>>>(AGG, W2c, b2c, H2, d_out, flag, NSPOT);
    y2_kernel<<<1250, 256, 0, stream>>>(H2, Wcat2, bcat2, Y, NSPOT);
    gat_kernel<<<5000, 256, 0, stream>>>(Y, 0,   192, off1, srcs1, attc3,  bc3,  AGG, 0,  NSPOT, E1N);
    gat_kernel<<<5000, 256, 0, stream>>>(Y, 384, 576, off2, srcs2, attc3p, bc3p, AGG, 64, NSPOT, E2N);
    // h4 -> d_out
    gemm_mfma<1, false, false, false, false, false, true, true><<<dim3(4, 313), 256, 0, stream>>>(
        AGG, W4c, b4c, d_out, flag, 0, OFF_H4, NSPOT, 256, 128, 128, 256, 256);
    // Xs = relu(h4 @ SE16)
    gemm_mfma<1, false, false, true, false, true, false, false><<<dim3(4, 313), 256, 0, stream>>>(
        d_out, SE16, nullptr, XS, flag, OFF_H4, 0, NSPOT, 256, 256, 256, 256, 256);
    cross_attn_kernel<<<5000, 256, 0, stream>>>(XG, XS, a1c, a2c, d_out, flag, NSPOT);
  } else {
    // fallback: round-2 proven path (small ws)
    u16* Y  = (u16*)R;
    u16* XG = Y;
    u16* XS = Y + 5120000;
    gemm_mfma<2, false, false, true, false, false, true, false><<<dim3(12, 157), 256, 0, stream>>>(
        spot_freq, Wcat1, bcat1, Y, flag, 0, 0, NSPOT, 768, 256, 256, 768, 768);
    gat_kernel<<<5000, 256, 0, stream>>>(Y, 0,   192, off1, srcs1, attc1,  bc1,  AGG, 0,  NSPOT, E1N);
    gat_kernel<<<5000, 256, 0, stream>>>(Y, 384, 576, off2, srcs2, attc1p, bc1p, AGG, 64, NSPOT, E2N);
    h2_kernel<<<1250, 256, 0, stream>>>(AGG, W2c, b2c, H2, d_out, flag, NSPOT);
    y2_kernel<<<1250, 256, 0, stream>>>(H2, Wcat2, bcat2, Y, NSPOT);
    gat_kernel<<<5000, 256, 0, stream>>>(Y, 0,   192, off1, srcs1, attc3,  bc3,  AGG, 0,  NSPOT, E1N);
    gat_kernel<<<5000, 256, 0, stream>>>(Y, 384, 576, off2, srcs2, attc3p, bc3p, AGG, 64, NSPOT, E2N);
    gemm_mfma<2, false, false, false, false, false, true, true><<<dim3(4, 157), 256, 0, stream>>>(
        AGG, W4c, b4c, d_out, flag, 0, OFF_H4, NSPOT, 256, 128, 128, 256, 256);
    gemm_mfma<2, false, false, true, true, true, false, false><<<dim3(4, 157), 256, 0, stream>>>(
        d_out, spot_eig, nullptr, XS, flag, OFF_H4, 0, NSPOT, 256, 256, 256, 256, 256);
    gemm_mfma<2, true, true, true, true, true, false, false><<<dim3(4, 157), 256, 0, stream>>>(
        gene_eig, gene_freq, nullptr, XG, flag, 0, 0, NSPOT, 256, NGENE, NSPOT, NGENE, 256);
    cross_attn_kernel<<<5000, 256, 0, stream>>>(XG, XS, a1c, a2c, d_out, flag, NSPOT);
  }

  (void)in_sizes; (void)n_in; (void)out_size; (void)ws_size;
}